// Round 1
// baseline (118.938 us; speedup 1.0000x reference)
//
#include <hip/hip_runtime.h>
#include <math.h>

// Problem: blocks [L=8, B=4, T=4096, D=1024] fp32, query [D], norm_weight [D].
// K = rmsnorm(blocks, w); logits[l,b,t] = q . K[l,b,t,:]; attn = softmax over l;
// out[b,t,:] = sum_l attn[l,b,t] * blocks[l,b,t,:].
//
// Strategy: one 256-thread block per (b,t). Each thread owns 4 consecutive d's
// (float4). All 8 l-rows are held in registers (8 x float4 = 32 VGPR payload).
// logits[l] = (sum_d q*w*x) * rsqrt(mean(x^2)+eps) -- rmsnorm never materialized.
// Single pass over HBM: blocks read once, out written once.

#define LL   8
#define DD   1024
#define TPB  256          // DD/4 threads, each owns a float4
#define EPSF 1e-6f

__global__ __launch_bounds__(TPB) void block_attn_kernel(
    const float* __restrict__ blocks,
    const float* __restrict__ query,
    const float* __restrict__ norm_weight,
    float* __restrict__ out,
    size_t l_stride)   // = B*T*D elements between consecutive l's
{
    const int bt  = blockIdx.x;          // flattened (b,t), 0..B*T-1
    const int tid = threadIdx.x;
    const int d0  = tid * 4;

    // q*w for this thread's 4 d's (weight folded into query)
    const float4 q = *reinterpret_cast<const float4*>(query + d0);
    const float4 w = *reinterpret_cast<const float4*>(norm_weight + d0);
    const float qw0 = q.x * w.x, qw1 = q.y * w.y, qw2 = q.z * w.z, qw3 = q.w * w.w;

    const float* base = blocks + (size_t)bt * DD + d0;

    float4 v[LL];
    float  ss[LL];   // partial sum of x^2 per l
    float  qd[LL];   // partial sum of q*w*x per l
#pragma unroll
    for (int l = 0; l < LL; ++l) {
        v[l]  = *reinterpret_cast<const float4*>(base + (size_t)l * l_stride);
        ss[l] = v[l].x * v[l].x + v[l].y * v[l].y + v[l].z * v[l].z + v[l].w * v[l].w;
        qd[l] = qw0 * v[l].x + qw1 * v[l].y + qw2 * v[l].z + qw3 * v[l].w;
    }

    // Wave (64-lane) butterfly reduce of the 16 partials
#pragma unroll
    for (int l = 0; l < LL; ++l) {
#pragma unroll
        for (int off = 32; off > 0; off >>= 1) {
            ss[l] += __shfl_down(ss[l], off, 64);
            qd[l] += __shfl_down(qd[l], off, 64);
        }
    }

    __shared__ float red[4][LL][2];      // 4 waves per block
    const int wave = tid >> 6;
    const int lane = tid & 63;
    if (lane == 0) {
#pragma unroll
        for (int l = 0; l < LL; ++l) {
            red[wave][l][0] = ss[l];
            red[wave][l][1] = qd[l];
        }
    }
    __syncthreads();

    __shared__ float attn_s[LL];
    if (tid == 0) {
        float logits[LL];
        float m = -INFINITY;
#pragma unroll
        for (int l = 0; l < LL; ++l) {
            const float s  = red[0][l][0] + red[1][l][0] + red[2][l][0] + red[3][l][0];
            const float qq = red[0][l][1] + red[1][l][1] + red[2][l][1] + red[3][l][1];
            const float lg = qq * rsqrtf(s * (1.0f / DD) + EPSF);
            logits[l] = lg;
            m = fmaxf(m, lg);
        }
        float sum = 0.f;
        float e[LL];
#pragma unroll
        for (int l = 0; l < LL; ++l) { e[l] = expf(logits[l] - m); sum += e[l]; }
        const float inv = 1.0f / sum;
#pragma unroll
        for (int l = 0; l < LL; ++l) attn_s[l] = e[l] * inv;
    }
    __syncthreads();

    float4 h = make_float4(0.f, 0.f, 0.f, 0.f);
#pragma unroll
    for (int l = 0; l < LL; ++l) {
        const float a = attn_s[l];
        h.x += a * v[l].x;
        h.y += a * v[l].y;
        h.z += a * v[l].z;
        h.w += a * v[l].w;
    }
    *reinterpret_cast<float4*>(out + (size_t)bt * DD + d0) = h;
}

extern "C" void kernel_launch(void* const* d_in, const int* in_sizes, int n_in,
                              void* d_out, int out_size, void* d_ws, size_t ws_size,
                              hipStream_t stream) {
    const float* blocks      = (const float*)d_in[0];
    const float* query       = (const float*)d_in[1];
    const float* norm_weight = (const float*)d_in[2];
    float*       out         = (float*)d_out;

    const size_t l_stride = (size_t)out_size;        // B*T*D
    const int    n_bt     = out_size / DD;           // B*T workgroups

    block_attn_kernel<<<n_bt, TPB, 0, stream>>>(blocks, query, norm_weight, out, l_stride);
}

// Round 3
// 99.870 us; speedup vs baseline: 1.1909x; 1.1909x over previous
//
#include <hip/hip_runtime.h>
#include <math.h>

// Problem: blocks [L=8, B=4, T=4096, D=1024] fp32, query [D], norm_weight [D].
// K = rmsnorm(blocks, w); logits[l,b,t] = q . K[l,b,t,:]; attn = softmax over l;
// out[b,t,:] = sum_l attn[l,b,t] * blocks[l,b,t,:].
//
// One 256-thread block per (b,t); each thread owns 4 d's (float4); all 8 l-rows
// live in registers. Single HBM pass (read blocks once, write out once).
//  - non-temporal loads/stores for the zero-reuse streams (blocks, out)
//    (must use clang ext_vector_type, not HIP_vector_type, for the builtin)
//  - folded multi-value wave reduce: 17 shuffles for all 16 sums
//  - 8-lane-parallel softmax

#define LL   8
#define DD   1024
#define TPB  256
#define EPSF 1e-6f

typedef float fx4 __attribute__((ext_vector_type(4)));

__global__ __launch_bounds__(TPB) void block_attn_kernel(
    const float* __restrict__ blocks,
    const float* __restrict__ query,
    const float* __restrict__ norm_weight,
    float* __restrict__ out,
    size_t l_stride)   // = B*T*D elements between consecutive l's
{
    const int bt   = blockIdx.x;
    const int tid  = threadIdx.x;
    const int lane = tid & 63;
    const int wave = tid >> 6;
    const int d0   = tid * 4;

    // q*w (weight folded into query); tiny, reused by all blocks -> cached loads
    const fx4 q = *reinterpret_cast<const fx4*>(query + d0);
    const fx4 w = *reinterpret_cast<const fx4*>(norm_weight + d0);
    const float qw0 = q.x * w.x, qw1 = q.y * w.y, qw2 = q.z * w.z, qw3 = q.w * w.w;

    const float* base = blocks + (size_t)bt * DD + d0;

    fx4   v[LL];
    float x[16];             // x[l] = sum x^2 partial; x[8+l] = sum q*w*x partial
#pragma unroll
    for (int l = 0; l < LL; ++l) {
        v[l] = __builtin_nontemporal_load(
                 reinterpret_cast<const fx4*>(base + (size_t)l * l_stride));
    }
#pragma unroll
    for (int l = 0; l < LL; ++l) {
        x[l]     = v[l].x * v[l].x + v[l].y * v[l].y + v[l].z * v[l].z + v[l].w * v[l].w;
        x[8 + l] = qw0 * v[l].x + qw1 * v[l].y + qw2 * v[l].z + qw3 * v[l].w;
    }

    // ---- Folded multi-value wave reduce: 16 values -> per-lane value (lane&15),
    // summed over all 64 lanes. 8+4+2+1+2 = 17 shuffles total.
    float y[8];
    {
        const bool b = lane & 1;
#pragma unroll
        for (int k = 0; k < 8; ++k) {
            const float mine = b ? x[2*k + 1] : x[2*k];
            const float oth  = b ? x[2*k]     : x[2*k + 1];
            y[k] = mine + __shfl_xor(oth, 1);
        }
    }
    float z[4];
    {
        const bool b = lane & 2;
#pragma unroll
        for (int j = 0; j < 4; ++j) {
            const float mine = b ? y[2*j + 1] : y[2*j];
            const float oth  = b ? y[2*j]     : y[2*j + 1];
            z[j] = mine + __shfl_xor(oth, 2);
        }
    }
    float t2[2];
    {
        const bool b = lane & 4;
#pragma unroll
        for (int i = 0; i < 2; ++i) {
            const float mine = b ? z[2*i + 1] : z[2*i];
            const float oth  = b ? z[2*i]     : z[2*i + 1];
            t2[i] = mine + __shfl_xor(oth, 4);
        }
    }
    float u;
    {
        const bool b = lane & 8;
        const float mine = b ? t2[1] : t2[0];
        const float oth  = b ? t2[0] : t2[1];
        u = mine + __shfl_xor(oth, 8);
    }
    u += __shfl_xor(u, 16);
    u += __shfl_xor(u, 32);
    // Now lane i holds the wave-total of x[i & 15].

    __shared__ float red[4][16];
    if (lane < 16) red[wave][lane] = u;
    __syncthreads();

    __shared__ float attn_s[LL];
    if (tid < 8) {
        const int l = tid;
        const float s  = red[0][l]     + red[1][l]     + red[2][l]     + red[3][l];
        const float qq = red[0][l + 8] + red[1][l + 8] + red[2][l + 8] + red[3][l + 8];
        const float lg = qq * rsqrtf(s * (1.0f / DD) + EPSF);
        float m = lg;
        m = fmaxf(m, __shfl_xor(m, 1));
        m = fmaxf(m, __shfl_xor(m, 2));
        m = fmaxf(m, __shfl_xor(m, 4));
        const float e = expf(lg - m);
        float ssum = e;
        ssum += __shfl_xor(ssum, 1);
        ssum += __shfl_xor(ssum, 2);
        ssum += __shfl_xor(ssum, 4);
        attn_s[l] = e / ssum;
    }
    __syncthreads();

    fx4 h = (fx4)(0.f);
#pragma unroll
    for (int l = 0; l < LL; ++l) {
        const float a = attn_s[l];
        h.x += a * v[l].x;
        h.y += a * v[l].y;
        h.z += a * v[l].z;
        h.w += a * v[l].w;
    }
    __builtin_nontemporal_store(h, reinterpret_cast<fx4*>(out + (size_t)bt * DD + d0));
}

extern "C" void kernel_launch(void* const* d_in, const int* in_sizes, int n_in,
                              void* d_out, int out_size, void* d_ws, size_t ws_size,
                              hipStream_t stream) {
    const float* blocks      = (const float*)d_in[0];
    const float* query       = (const float*)d_in[1];
    const float* norm_weight = (const float*)d_in[2];
    float*       out         = (float*)d_out;

    const size_t l_stride = (size_t)out_size;   // B*T*D
    const int    n_bt     = out_size / DD;      // B*T workgroups

    block_attn_kernel<<<n_bt, TPB, 0, stream>>>(blocks, query, norm_weight, out, l_stride);
}